// Round 19
// baseline (2099.768 us; speedup 1.0000x reference)
//
#include <hip/hip_runtime.h>
#include <math.h>

#define N_NODES 20000
#define N_EDGES 320000
#define T_STEPS 16
#define TB 8                       // timesteps per half-batch
#define RB_ROWS (N_NODES * TB)     // 160000 rows = 1250 * 128
#define F_INDIM 128
#define HC 256
#define HEADS 4
#define CDIM 64
#define G3 192
#define EPN (N_EDGES + N_NODES)    // 340000 edges incl self-loops per t
#define CSR_NB 20                  // histogram blocks per timestep
#define CSR_EPB 16000              // edges per histogram block

typedef __attribute__((ext_vector_type(8))) short bf16x8;
typedef __attribute__((ext_vector_type(8))) unsigned short ushort8;
typedef __attribute__((ext_vector_type(4))) float f32x4;
typedef __attribute__((ext_vector_type(4))) _Float16 half4;
typedef __attribute__((ext_vector_type(8))) _Float16 half8;

__device__ inline unsigned short f2bf(float x) {
    unsigned int u = __builtin_bit_cast(unsigned int, x);
    u += 0x7fffu + ((u >> 16) & 1u);
    return (unsigned short)(u >> 16);
}
__device__ inline void split_hilo(float x, unsigned short& h, unsigned short& l) {
    h = f2bf(x);
    float hf = __builtin_bit_cast(float, (unsigned int)h << 16);
    l = f2bf(x - hf);
}
__device__ inline ushort8 f4_to_hilo(float4 v) {
    ushort8 o;
    split_hilo(v.x, ((unsigned short*)&o)[0], ((unsigned short*)&o)[1]);
    split_hilo(v.y, ((unsigned short*)&o)[2], ((unsigned short*)&o)[3]);
    split_hilo(v.z, ((unsigned short*)&o)[4], ((unsigned short*)&o)[5]);
    split_hilo(v.w, ((unsigned short*)&o)[6], ((unsigned short*)&o)[7]);
    return o;
}
__device__ inline float fsig(float x) { return 1.f / (1.f + __expf(-x)); }
__device__ inline float ftanh(float x) {
    x = fminf(fmaxf(x, -15.f), 15.f);
    float e = __expf(2.f * x);
    return (e - 1.f) / (e + 1.f);
}

// ---------------- conversions ----------------

__global__ void k_wsplit(const float* __restrict__ W, unsigned short* __restrict__ Wt,
                         int K, int Ncol) {
    int idx = blockIdx.x * 256 + threadIdx.x;
    if (idx >= K * Ncol) return;
    int k = idx / Ncol, c = idx - k * Ncol;
    unsigned short h, l;
    split_hilo(W[idx], h, l);
    Wt[(size_t)c * 2 * K + 2 * k] = h;
    Wt[(size_t)c * 2 * K + 2 * k + 1] = l;
}

__global__ void k_whalf(const float* __restrict__ W, _Float16* __restrict__ Wt,
                        int K, int Ncol) {
    int idx = blockIdx.x * 256 + threadIdx.x;
    if (idx >= K * Ncol) return;
    int k = idx / Ncol, c = idx - k * Ncol;
    Wt[(size_t)c * K + k] = (_Float16)W[idx];
}

// ---------------- CSR build: LDS-histogram counting sort, no global atomics ----------------

__global__ __launch_bounds__(1024) void k_csr_hist(const int* __restrict__ ei,
                                                   unsigned int* __restrict__ partial,
                                                   unsigned short* __restrict__ lrank16) {
    __shared__ unsigned int hist[N_NODES];   // 80 KB
    const int t = blockIdx.y, b = blockIdx.x;
    const int tid = threadIdx.x;
    for (int i = tid; i < N_NODES; i += 1024) hist[i] = 0;
    __syncthreads();
    const int* dst = ei + (size_t)t * 2 * N_EDGES + N_EDGES;
    const int e1 = min(b * CSR_EPB + CSR_EPB, N_EDGES);
    for (int e = b * CSR_EPB + tid; e < e1; e += 1024) {
        unsigned int lr = atomicAdd(&hist[dst[e]], 1u);
        lrank16[(size_t)t * N_EDGES + e] = (unsigned short)lr;
    }
    __syncthreads();
    unsigned int* pp = partial + ((size_t)t * CSR_NB + b) * N_NODES;
    for (int i = tid; i < N_NODES; i += 1024) pp[i] = hist[i];
}

__global__ void k_csr_colscan(unsigned int* __restrict__ partial,
                              unsigned int* __restrict__ total) {
    int idx = blockIdx.x * 256 + threadIdx.x;   // t*N_NODES + d
    if (idx >= T_STEPS * N_NODES) return;
    int t = idx / N_NODES;
    int d = idx - t * N_NODES;
    unsigned int* pb = partial + (size_t)t * CSR_NB * N_NODES + d;
    unsigned int acc = 0;
#pragma unroll
    for (int b = 0; b < CSR_NB; ++b) {
        unsigned int c = pb[(size_t)b * N_NODES];
        pb[(size_t)b * N_NODES] = acc;
        acc += c;
    }
    total[idx] = acc + 1;   // + self-loop
}

__global__ __launch_bounds__(1024) void k_csr_scan(const unsigned int* __restrict__ total,
                                                   int* __restrict__ off_all,
                                                   unsigned short* __restrict__ csr16) {
    __shared__ int sdata[1024];
    const int t = blockIdx.x;
    const unsigned int* tot = total + (size_t)t * N_NODES;
    int* off = off_all + t * (N_NODES + 1);
    unsigned short* cs = csr16 + (size_t)t * EPN;
    const int tid = threadIdx.x;
    const int ITEMS = (N_NODES + 1023) / 1024;   // 20
    const int start = tid * ITEMS;
    int local = 0;
    for (int i = 0; i < ITEMS; ++i) {
        int d = start + i;
        if (d < N_NODES) local += tot[d];
    }
    sdata[tid] = local;
    __syncthreads();
    for (int s = 1; s < 1024; s <<= 1) {
        int v = (tid >= s) ? sdata[tid - s] : 0;
        __syncthreads();
        sdata[tid] += v;
        __syncthreads();
    }
    int run = sdata[tid] - local;   // exclusive
    for (int i = 0; i < ITEMS; ++i) {
        int d = start + i;
        if (d < N_NODES) {
            off[d] = run;
            cs[run] = (unsigned short)d;   // self-loop in slot 0
            run += tot[d];
        }
    }
    if (tid == 0) off[N_NODES] = EPN;
}

__global__ void k_csr_fold(unsigned int* __restrict__ partial,
                           const int* __restrict__ off_all) {
    int idx = blockIdx.x * 256 + threadIdx.x;
    if (idx >= T_STEPS * CSR_NB * N_NODES) return;
    int t = idx / (CSR_NB * N_NODES);
    int rem = idx - t * (CSR_NB * N_NODES);
    int d = rem % N_NODES;
    partial[idx] += (unsigned int)(off_all[t * (N_NODES + 1) + d] + 1);
}

__global__ void k_csr_fill(const int* __restrict__ ei,
                           const unsigned int* __restrict__ partial,
                           const unsigned short* __restrict__ lrank16,
                           unsigned short* __restrict__ csr16) {
    const int bid = blockIdx.x;
    const int t = bid & 15;
    const int i = bid >> 4;
    const int e = i * 256 + threadIdx.x;
    const int* ep = ei + (size_t)t * 2 * N_EDGES;
    int s = ep[e], d = ep[N_EDGES + e];
    int b = e / CSR_EPB;
    unsigned int pos = partial[((size_t)t * CSR_NB + b) * N_NODES + d]
                     + lrank16[(size_t)t * N_EDGES + e];
    csr16[(size_t)t * EPN + pos] = (unsigned short)s;
}

// ---------------- MFMA GEMM (+fused attention-dot epilogue) ----------------

template <bool XMAP, bool ATTN, bool CHALF, int BN, bool AF32, int DT>
__global__ __launch_bounds__(256) void k_gemm_mfma(const unsigned short* __restrict__ A, int lda,
                                                   const unsigned short* __restrict__ Bt,
                                                   float* __restrict__ C, int ldc,
                                                   int K2, int tbase,
                                                   const float* __restrict__ a_src,
                                                   const float* __restrict__ a_dst,
                                                   float* __restrict__ asb,
                                                   float* __restrict__ adb) {
    __shared__ unsigned short sA[128][40];
    __shared__ unsigned short sB[BN][40];
    const int NJ = BN / 16;
    const int tid = threadIdx.x;
    const int wid = tid >> 6, lane = tid & 63;
    const int row0 = blockIdx.y * 128;
    const int col0 = blockIdx.x * BN;

    const int ar = tid >> 1, aq = (tid & 1) * 8;
    const int bc = tid >> 2, bq = (tid & 3) * 8;

    int l = row0 + ar;
    int rg;
    if (XMAP) { int tl = l / N_NODES; int s = l - tl * N_NODES; rg = s * T_STEPS + tbase + tl; }
    else rg = l;
    const unsigned short* Arow = A + (size_t)rg * lda;
    const float* Arowf = (const float*)A + (size_t)rg * lda;
    const unsigned short* Brow = Bt + (size_t)(col0 + bc) * K2;
    const unsigned short* Brow2 = (BN == 128) ? (Bt + (size_t)(col0 + bc + 64) * K2) : Brow;

    const int fr = lane & 15;
    const int kg = lane >> 4;

    f32x4 acc[2][NJ] = {};

    for (int kk = 0; kk < K2; kk += 32) {
        ushort8 a0, a1;
        if (AF32) {
            float4 fa0 = *(const float4*)(Arowf + ((kk + aq) >> 1));
            float4 fa1 = *(const float4*)(Arowf + ((kk + aq) >> 1) + 8);
            a0 = f4_to_hilo(fa0);
            a1 = f4_to_hilo(fa1);
        } else {
            a0 = *(const ushort8*)(Arow + kk + aq);
            a1 = *(const ushort8*)(Arow + kk + aq + 16);
        }
        ushort8 b0 = *(const ushort8*)(Brow + kk + bq);
        ushort8 b1;
        if (BN == 128) b1 = *(const ushort8*)(Brow2 + kk + bq);
        *(ushort8*)&sA[ar][aq] = a0;
        *(ushort8*)&sA[ar][aq + 16] = a1;
        *(ushort8*)&sB[bc][bq] = b0;
        if (BN == 128) *(ushort8*)&sB[bc + 64][bq] = b1;
        __syncthreads();
        bf16x8 af[2], bfv[NJ];
#pragma unroll
        for (int i = 0; i < 2; ++i)
            af[i] = *(const bf16x8*)&sA[wid * 32 + i * 16 + fr][kg * 8];
#pragma unroll
        for (int j = 0; j < NJ; ++j)
            bfv[j] = *(const bf16x8*)&sB[j * 16 + fr][kg * 8];
#pragma unroll
        for (int i = 0; i < 2; ++i)
#pragma unroll
            for (int j = 0; j < NJ; ++j) {
                if (DT == 0)
                    acc[i][j] = __builtin_amdgcn_mfma_f32_16x16x32_bf16(af[i], bfv[j],
                                                                        acc[i][j], 0, 0, 0);
                else
                    acc[i][j] = __builtin_amdgcn_mfma_f32_16x16x32_f16(
                        __builtin_bit_cast(half8, af[i]), __builtin_bit_cast(half8, bfv[j]),
                        acc[i][j], 0, 0, 0);
            }
        __syncthreads();
    }
#pragma unroll
    for (int i = 0; i < 2; ++i)
#pragma unroll
        for (int j = 0; j < NJ; ++j) {
            int col = col0 + j * 16 + fr;
#pragma unroll
            for (int r = 0; r < 4; ++r) {
                int row = row0 + wid * 32 + i * 16 + kg * 4 + r;
                if (CHALF) {
                    _Float16* Ch = (_Float16*)C;
                    Ch[(size_t)row * ldc + col] = (_Float16)acc[i][j][r];
                } else {
                    C[(size_t)row * ldc + col] = acc[i][j][r];
                }
            }
        }

    if (ATTN) {
#pragma unroll
        for (int half = 0; half < BN / 64; ++half) {
            const int h_idx = (col0 >> 6) + half;
            float wa[4], wb[4];
#pragma unroll
            for (int j = 0; j < 4; ++j) {
                wa[j] = a_src[h_idx * 64 + j * 16 + fr];
                wb[j] = a_dst[h_idx * 64 + j * 16 + fr];
            }
#pragma unroll
            for (int i = 0; i < 2; ++i)
#pragma unroll
                for (int r = 0; r < 4; ++r) {
                    float sa = 0.f, sd = 0.f;
#pragma unroll
                    for (int j = 0; j < 4; ++j) {
                        sa = fmaf(acc[i][half * 4 + j][r], wa[j], sa);
                        sd = fmaf(acc[i][half * 4 + j][r], wb[j], sd);
                    }
#pragma unroll
                    for (int s = 1; s <= 8; s <<= 1) {
                        sa += __shfl_xor(sa, s, 64);
                        sd += __shfl_xor(sd, s, 64);
                    }
                    if (fr == 0) {
                        int row = row0 + wid * 32 + i * 16 + kg * 4 + r;
                        asb[(size_t)row * 4 + h_idx] = sa;
                        adb[(size_t)row * 4 + h_idx] = sd;
                    }
                }
        }
    }
}

// ---------------- GAT aggregation: head-quarter blocks (L2-resident gathers) ----------------
// bid = (q*5000 + nb)*8 + tl  ->  XCD = tl, q-phases sequential in time per XCD.
// Block = 4 waves = 4 dests; wave lane = e4*16 + c16: 4 edges in flight x 64 ch (head q).
// CONCAT: write quarter with bias+relu. !CONCAT: write raw per-head val (combine later).

template <bool CONCAT>
__global__ __launch_bounds__(256) void k_aggq(const _Float16* __restrict__ hfeat,
                                              const float* __restrict__ asb,
                                              const float* __restrict__ adb,
                                              const int* __restrict__ off_all,
                                              const unsigned short* __restrict__ csr16,
                                              const float* __restrict__ bias,
                                              _Float16* __restrict__ out, int tbase) {
    const int bid = blockIdx.x;
    const int tl = bid & 7;
    const int rem = bid >> 3;
    const int nb = rem % (N_NODES / 4);
    const int q = rem / (N_NODES / 4);
    const int t = tbase + tl;
    const int wid = threadIdx.x >> 6;
    const int d = nb * 4 + wid;
    const int lane = threadIdx.x & 63;
    const int e4 = lane >> 4;
    const int c16 = lane & 15;

    const int* off = off_all + (size_t)t * (N_NODES + 1);
    const int beg = off[d];
    const int deg = off[d + 1] - beg;
    const unsigned short* cs = csr16 + (size_t)t * EPN + beg;
    const float* asl = asb + (size_t)tl * N_NODES * HEADS;
    const _Float16* feat = hfeat + (size_t)tl * N_NODES * HC + q * 64 + c16 * 4;
    const float adh = adb[((size_t)tl * N_NODES + d) * HEADS + q];

    float ax = 0.f, ay = 0.f, az = 0.f, aw = 0.f, dlane = 0.f;

    // prologue: first 4 edges' score chain
    int sreg = 0;
    float araw = 0.f;
    if (e4 < deg) {
        sreg = cs[e4];
        araw = asl[sreg * 4 + q];
    }

    for (int base = 0; base < deg; base += 4) {
        bool act = (base + e4 < deg);
        float wme = 0.f;
        if (act) {
            float sc = araw + adh;
            sc = sc > 0.f ? sc : 0.2f * sc;
            wme = __expf(sc);
        }
        dlane += wme;

        int nxt = base + 4;
        int sregN = 0;
        float arawN = 0.f;
        if (nxt + e4 < deg) {
            sregN = cs[nxt + e4];
            arawN = asl[sregN * 4 + q];
        }

        if (act) {
            half4 v = *(const half4*)(feat + (size_t)sreg * HC);
            ax = fmaf(wme, (float)v[0], ax);
            ay = fmaf(wme, (float)v[1], ay);
            az = fmaf(wme, (float)v[2], az);
            aw = fmaf(wme, (float)v[3], aw);
        }
        sreg = sregN;
        araw = arawN;
    }

    // reduce across the 4 e4-groups (channels are per-c16, identical across groups)
    ax += __shfl_xor(ax, 16, 64); ax += __shfl_xor(ax, 32, 64);
    ay += __shfl_xor(ay, 16, 64); ay += __shfl_xor(ay, 32, 64);
    az += __shfl_xor(az, 16, 64); az += __shfl_xor(az, 32, 64);
    aw += __shfl_xor(aw, 16, 64); aw += __shfl_xor(aw, 32, 64);
    float denom = dlane;
    denom += __shfl_xor(denom, 16, 64); denom += __shfl_xor(denom, 32, 64);
    float inv = 1.f / (denom + 1e-16f);
    ax *= inv; ay *= inv; az *= inv; aw *= inv;

    if (e4 == 0) {
        half4 o;
        if (CONCAT) {
            float4 b = ((const float4*)bias)[q * 16 + c16];
            o[0] = (_Float16)fmaxf(ax + b.x, 0.f);
            o[1] = (_Float16)fmaxf(ay + b.y, 0.f);
            o[2] = (_Float16)fmaxf(az + b.z, 0.f);
            o[3] = (_Float16)fmaxf(aw + b.w, 0.f);
        } else {
            o[0] = (_Float16)ax; o[1] = (_Float16)ay;
            o[2] = (_Float16)az; o[3] = (_Float16)aw;
        }
        *(half4*)(out + ((size_t)tl * N_NODES + d) * HC + q * 64 + c16 * 4) = o;
    }
}

// combine for layer 2: mean over the 4 head vals + bias + relu -> g2 [node][t][64]
__global__ void k_aggmean(const _Float16* __restrict__ valq, const float* __restrict__ bias,
                          _Float16* __restrict__ g2, int tbase) {
    int idx = blockIdx.x * 256 + threadIdx.x;
    if (idx >= TB * N_NODES * 16) return;
    int c16 = idx & 15;
    int rem = idx >> 4;
    int d = rem % N_NODES;
    int tl = rem / N_NODES;
    const _Float16* vp = valq + ((size_t)tl * N_NODES + d) * HC + c16 * 4;
    half4 v0 = *(const half4*)(vp);
    half4 v1 = *(const half4*)(vp + 64);
    half4 v2 = *(const half4*)(vp + 128);
    half4 v3 = *(const half4*)(vp + 192);
    float4 b = ((const float4*)bias)[c16];
    half4 o;
    o[0] = (_Float16)fmaxf(0.25f * ((float)v0[0] + (float)v1[0] + (float)v2[0] + (float)v3[0]) + b.x, 0.f);
    o[1] = (_Float16)fmaxf(0.25f * ((float)v0[1] + (float)v1[1] + (float)v2[1] + (float)v3[1]) + b.y, 0.f);
    o[2] = (_Float16)fmaxf(0.25f * ((float)v0[2] + (float)v1[2] + (float)v2[2] + (float)v3[2]) + b.z, 0.f);
    o[3] = (_Float16)fmaxf(0.25f * ((float)v0[3] + (float)v1[3] + (float)v2[3] + (float)v3[3]) + b.w, 0.f);
    *(half4*)(g2 + ((size_t)d * T_STEPS + tbase + tl) * CDIM + c16 * 4) = o;
}

// ---------------- persistent GRU (h-side GEMV only) + final linear ----------------

#define GRU_NPB 40
#define GRU_THREADS 512

__global__ __launch_bounds__(GRU_THREADS, 4) void k_gru_all(const _Float16* __restrict__ GI,
                                                            const float* __restrict__ Whh,
                                                            const float* __restrict__ bih,
                                                            const float* __restrict__ bhh,
                                                            const float* __restrict__ Wout,
                                                            const float* __restrict__ bout,
                                                            float* __restrict__ out) {
    __shared__ f32x4 sWp[16 * 3 * 64];   // 48 KB: [k4][p][c]
    __shared__ float sH[GRU_NPB][68];
    const int tid = threadIdx.x;
    const int c = tid & 63;
    const int ng = tid >> 6;
    const int n0 = ng * 5;
    const int nid0 = blockIdx.x * GRU_NPB + n0;

    for (int i = tid; i < 16 * 3 * 64; i += GRU_THREADS) {
        int k4 = i / 192, rem = i - k4 * 192;
        int pp = rem >> 6, cc = rem & 63;
        f32x4 w;
#pragma unroll
        for (int q = 0; q < 4; ++q) w[q] = Whh[(k4 * 4 + q) * G3 + pp * 64 + cc];
        sWp[i] = w;
    }
    for (int i = tid; i < GRU_NPB * 68; i += GRU_THREADS) ((float*)sH)[i] = 0.f;
    __syncthreads();

    const float bi0 = bih[c], bi1 = bih[64 + c], bi2 = bih[128 + c];
    const float bh0 = bhh[c], bh1 = bhh[64 + c], bh2 = bhh[128 + c];

    for (int t = 0; t < T_STEPS; ++t) {
        float gi0[5], gi1[5], gi2[5];
#pragma unroll
        for (int n = 0; n < 5; ++n) {
            const _Float16* gp = GI + ((size_t)(nid0 + n) * T_STEPS + t) * G3;
            gi0[n] = (float)gp[c]; gi1[n] = (float)gp[64 + c]; gi2[n] = (float)gp[128 + c];
        }
        float a0[5] = {}, a1[5] = {}, a2[5] = {};
#pragma unroll 4
        for (int k4 = 0; k4 < 16; ++k4) {
            f32x4 h4[5];
#pragma unroll
            for (int n = 0; n < 5; ++n) h4[n] = *(const f32x4*)&sH[n0 + n][k4 * 4];
            f32x4 w0 = sWp[(k4 * 3 + 0) * 64 + c];
            f32x4 w1 = sWp[(k4 * 3 + 1) * 64 + c];
            f32x4 w2 = sWp[(k4 * 3 + 2) * 64 + c];
#pragma unroll
            for (int q = 0; q < 4; ++q)
#pragma unroll
                for (int n = 0; n < 5; ++n) {
                    float hv = h4[n][q];
                    a0[n] = fmaf(hv, w0[q], a0[n]);
                    a1[n] = fmaf(hv, w1[q], a1[n]);
                    a2[n] = fmaf(hv, w2[q], a2[n]);
                }
        }
#pragma unroll
        for (int n = 0; n < 5; ++n) {
            float r = fsig(gi0[n] + bi0 + a0[n] + bh0);
            float z = fsig(gi1[n] + bi1 + a1[n] + bh1);
            float g = ftanh(gi2[n] + bi2 + r * (a2[n] + bh2));
            sH[n0 + n][c] = (1.f - z) * g + z * sH[n0 + n][c];
        }
    }

    float wc = Wout[c];
    float b0 = bout[0];
#pragma unroll
    for (int n = 0; n < 5; ++n) {
        float v = sH[n0 + n][c] * wc;
#pragma unroll
        for (int s = 32; s >= 1; s >>= 1) v += __shfl_xor(v, s, 64);
        if (c == 0) out[nid0 + n] = v + b0;
    }
}

// ---------------- launch ----------------

extern "C" void kernel_launch(void* const* d_in, const int* in_sizes, int n_in,
                              void* d_out, int out_size, void* d_ws, size_t ws_size,
                              hipStream_t stream) {
    const float* x   = (const float*)d_in[0];
    const int*   ei  = (const int*)d_in[1];
    const float* W1  = (const float*)d_in[2];
    const float* as1 = (const float*)d_in[3];
    const float* ad1 = (const float*)d_in[4];
    const float* b1  = (const float*)d_in[5];
    const float* W2  = (const float*)d_in[6];
    const float* as2 = (const float*)d_in[7];
    const float* ad2 = (const float*)d_in[8];
    const float* b2  = (const float*)d_in[9];
    const float* Wih = (const float*)d_in[10];
    const float* Whh = (const float*)d_in[11];
    const float* bih = (const float*)d_in[12];
    const float* bhh = (const float*)d_in[13];
    const float* Wout = (const float*)d_in[14];
    const float* bout = (const float*)d_in[15];

    char* p = (char*)d_ws;
    _Float16* h_half = (_Float16*)p;  p += 81920000;   // [8][20000][256] fp16
    _Float16* g1_f16 = (_Float16*)p;  p += 81920000;   // [8][20000][256] fp16 (also valq scratch)
    _Float16* g2_f16 = (_Float16*)p;  p += 40960000;   // [20000][16][64] fp16
    _Float16* GI_all = (_Float16*)p;  p += 122880000;  // [320000][192] fp16
    float* asb = (float*)p;  p += 2560000;
    float* adb = (float*)p;  p += 2560000;
    unsigned short* w1t = (unsigned short*)p;  p += 131072;   // 256 x 256 bf16 hilo
    _Float16* w2h = (_Float16*)p;  p += 131072;               // 256 x 256 fp16
    _Float16* wihh = (_Float16*)p;  p += 24576;               // 192 x 64 fp16
    int* off_all = (int*)p;  p += 1280064;
    unsigned short* csr16 = (unsigned short*)p;  p += 10880000;
    unsigned int* partial = (unsigned int*)p;  p += (size_t)T_STEPS * CSR_NB * N_NODES * 4;
    unsigned int* total = (unsigned int*)p;  p += (size_t)T_STEPS * N_NODES * 4;
    unsigned short* lrank16 = (unsigned short*)p;  p += (size_t)T_STEPS * N_EDGES * 2;

    dim3 thr(256);
    const int AGGQ_GRID = HEADS * (N_NODES / 4) * 8;   // 160000 blocks

    // weight conversions
    k_wsplit<<<(F_INDIM * HC + 255) / 256, thr, 0, stream>>>(W1, w1t, F_INDIM, HC);
    k_whalf<<<(HC * HC + 255) / 256, thr, 0, stream>>>(W2, w2h, HC, HC);
    k_whalf<<<(CDIM * G3 + 255) / 256, thr, 0, stream>>>(Wih, wihh, CDIM, G3);

    // CSR: hist(+lrank) -> colscan -> scan -> fold -> parallel scatter fill
    k_csr_hist<<<dim3(CSR_NB, T_STEPS), 1024, 0, stream>>>(ei, partial, lrank16);
    k_csr_colscan<<<(T_STEPS * N_NODES + 255) / 256, thr, 0, stream>>>(partial, total);
    k_csr_scan<<<T_STEPS, 1024, 0, stream>>>(total, off_all, csr16);
    k_csr_fold<<<(T_STEPS * CSR_NB * N_NODES + 255) / 256, thr, 0, stream>>>(partial, off_all);
    k_csr_fill<<<(N_EDGES / 256) * T_STEPS, thr, 0, stream>>>(ei, partial, lrank16, csr16);

    for (int hb = 0; hb < 2; ++hb) {
        const int tbase = hb * TB;
        // GAT layer 1: fp32 x staged+split in-kernel (bf16 hilo MFMA); fp16 feature out
        k_gemm_mfma<true, true, true, 128, true, 0><<<dim3(2, RB_ROWS / 128), thr, 0, stream>>>(
            (const unsigned short*)x, F_INDIM, w1t, (float*)h_half, HC, 2 * F_INDIM, tbase,
            as1, ad1, asb, adb);
        k_aggq<true><<<AGGQ_GRID, thr, 0, stream>>>(
            h_half, asb, adb, off_all, csr16, b1, g1_f16, tbase);
        // GAT layer 2: fp16 x fp16 MFMA, K=256
        k_gemm_mfma<false, true, true, 128, false, 1><<<dim3(2, RB_ROWS / 128), thr, 0, stream>>>(
            (const unsigned short*)g1_f16, HC, (const unsigned short*)w2h, (float*)h_half, HC,
            HC, tbase, as2, ad2, asb, adb);
        // layer-2 agg: per-head vals into g1_f16 (dead after GEMM2), then combine
        k_aggq<false><<<AGGQ_GRID, thr, 0, stream>>>(
            h_half, asb, adb, off_all, csr16, nullptr, g1_f16, tbase);
        k_aggmean<<<(TB * N_NODES * 16 + 255) / 256, thr, 0, stream>>>(g1_f16, b2, g2_f16, tbase);
    }

    // GI = g2 @ Wih for all (node, t) rows: fp16 MFMA, K=64, fp16 output
    k_gemm_mfma<false, false, true, 64, false, 1><<<dim3(3, N_NODES * T_STEPS / 128), thr, 0,
                                                    stream>>>(
        (const unsigned short*)g2_f16, CDIM, (const unsigned short*)wihh, (float*)GI_all, G3,
        CDIM, 0, nullptr, nullptr, nullptr, nullptr);

    k_gru_all<<<N_NODES / GRU_NPB, GRU_THREADS, 0, stream>>>(GI_all, Whh, bih, bhh, Wout, bout,
                                                            (float*)d_out);
}

// Round 20
// 1174.346 us; speedup vs baseline: 1.7880x; 1.7880x over previous
//
#include <hip/hip_runtime.h>
#include <math.h>

#define N_NODES 20000
#define N_EDGES 320000
#define T_STEPS 16
#define TB 8                       // timesteps per half-batch
#define RB_ROWS (N_NODES * TB)     // 160000 rows = 1250 * 128
#define F_INDIM 128
#define HC 256
#define HEADS 4
#define CDIM 64
#define G3 192
#define EPN (N_EDGES + N_NODES)    // 340000 edges incl self-loops per t
#define CSR_NB 20                  // histogram blocks per timestep
#define CSR_EPB 16000              // edges per histogram block

typedef __attribute__((ext_vector_type(8))) short bf16x8;
typedef __attribute__((ext_vector_type(8))) unsigned short ushort8;
typedef __attribute__((ext_vector_type(4))) float f32x4;
typedef __attribute__((ext_vector_type(4))) _Float16 half4;
typedef __attribute__((ext_vector_type(8))) _Float16 half8;

__device__ inline unsigned short f2bf(float x) {
    unsigned int u = __builtin_bit_cast(unsigned int, x);
    u += 0x7fffu + ((u >> 16) & 1u);
    return (unsigned short)(u >> 16);
}
__device__ inline void split_hilo(float x, unsigned short& h, unsigned short& l) {
    h = f2bf(x);
    float hf = __builtin_bit_cast(float, (unsigned int)h << 16);
    l = f2bf(x - hf);
}
__device__ inline ushort8 f4_to_hilo(float4 v) {
    ushort8 o;
    split_hilo(v.x, ((unsigned short*)&o)[0], ((unsigned short*)&o)[1]);
    split_hilo(v.y, ((unsigned short*)&o)[2], ((unsigned short*)&o)[3]);
    split_hilo(v.z, ((unsigned short*)&o)[4], ((unsigned short*)&o)[5]);
    split_hilo(v.w, ((unsigned short*)&o)[6], ((unsigned short*)&o)[7]);
    return o;
}
__device__ inline float fsig(float x) { return 1.f / (1.f + __expf(-x)); }
__device__ inline float ftanh(float x) {
    x = fminf(fmaxf(x, -15.f), 15.f);
    float e = __expf(2.f * x);
    return (e - 1.f) / (e + 1.f);
}

// ---------------- conversions ----------------

__global__ void k_wsplit(const float* __restrict__ W, unsigned short* __restrict__ Wt,
                         int K, int Ncol) {
    int idx = blockIdx.x * 256 + threadIdx.x;
    if (idx >= K * Ncol) return;
    int k = idx / Ncol, c = idx - k * Ncol;
    unsigned short h, l;
    split_hilo(W[idx], h, l);
    Wt[(size_t)c * 2 * K + 2 * k] = h;
    Wt[(size_t)c * 2 * K + 2 * k + 1] = l;
}

__global__ void k_whalf(const float* __restrict__ W, _Float16* __restrict__ Wt,
                        int K, int Ncol) {
    int idx = blockIdx.x * 256 + threadIdx.x;
    if (idx >= K * Ncol) return;
    int k = idx / Ncol, c = idx - k * Ncol;
    Wt[(size_t)c * K + k] = (_Float16)W[idx];
}

// ---------------- CSR build: LDS-histogram counting sort, no global atomics ----------------

__global__ __launch_bounds__(1024) void k_csr_hist(const int* __restrict__ ei,
                                                   unsigned int* __restrict__ partial,
                                                   unsigned short* __restrict__ lrank16) {
    __shared__ unsigned int hist[N_NODES];   // 80 KB
    const int t = blockIdx.y, b = blockIdx.x;
    const int tid = threadIdx.x;
    for (int i = tid; i < N_NODES; i += 1024) hist[i] = 0;
    __syncthreads();
    const int* dst = ei + (size_t)t * 2 * N_EDGES + N_EDGES;
    const int e1 = min(b * CSR_EPB + CSR_EPB, N_EDGES);
    for (int e = b * CSR_EPB + tid; e < e1; e += 1024) {
        unsigned int lr = atomicAdd(&hist[dst[e]], 1u);
        lrank16[(size_t)t * N_EDGES + e] = (unsigned short)lr;
    }
    __syncthreads();
    unsigned int* pp = partial + ((size_t)t * CSR_NB + b) * N_NODES;
    for (int i = tid; i < N_NODES; i += 1024) pp[i] = hist[i];
}

__global__ void k_csr_colscan(unsigned int* __restrict__ partial,
                              unsigned int* __restrict__ total) {
    int idx = blockIdx.x * 256 + threadIdx.x;   // t*N_NODES + d
    if (idx >= T_STEPS * N_NODES) return;
    int t = idx / N_NODES;
    int d = idx - t * N_NODES;
    unsigned int* pb = partial + (size_t)t * CSR_NB * N_NODES + d;
    unsigned int acc = 0;
#pragma unroll
    for (int b = 0; b < CSR_NB; ++b) {
        unsigned int c = pb[(size_t)b * N_NODES];
        pb[(size_t)b * N_NODES] = acc;
        acc += c;
    }
    total[idx] = acc + 1;   // + self-loop
}

__global__ __launch_bounds__(1024) void k_csr_scan(const unsigned int* __restrict__ total,
                                                   int* __restrict__ off_all,
                                                   unsigned short* __restrict__ csr16) {
    __shared__ int sdata[1024];
    const int t = blockIdx.x;
    const unsigned int* tot = total + (size_t)t * N_NODES;
    int* off = off_all + t * (N_NODES + 1);
    unsigned short* cs = csr16 + (size_t)t * EPN;
    const int tid = threadIdx.x;
    const int ITEMS = (N_NODES + 1023) / 1024;   // 20
    const int start = tid * ITEMS;
    int local = 0;
    for (int i = 0; i < ITEMS; ++i) {
        int d = start + i;
        if (d < N_NODES) local += tot[d];
    }
    sdata[tid] = local;
    __syncthreads();
    for (int s = 1; s < 1024; s <<= 1) {
        int v = (tid >= s) ? sdata[tid - s] : 0;
        __syncthreads();
        sdata[tid] += v;
        __syncthreads();
    }
    int run = sdata[tid] - local;   // exclusive
    for (int i = 0; i < ITEMS; ++i) {
        int d = start + i;
        if (d < N_NODES) {
            off[d] = run;
            cs[run] = (unsigned short)d;   // self-loop in slot 0
            run += tot[d];
        }
    }
    if (tid == 0) off[N_NODES] = EPN;
}

__global__ void k_csr_fold(unsigned int* __restrict__ partial,
                           const int* __restrict__ off_all) {
    int idx = blockIdx.x * 256 + threadIdx.x;
    if (idx >= T_STEPS * CSR_NB * N_NODES) return;
    int t = idx / (CSR_NB * N_NODES);
    int rem = idx - t * (CSR_NB * N_NODES);
    int d = rem % N_NODES;
    partial[idx] += (unsigned int)(off_all[t * (N_NODES + 1) + d] + 1);
}

__global__ void k_csr_fill(const int* __restrict__ ei,
                           const unsigned int* __restrict__ partial,
                           const unsigned short* __restrict__ lrank16,
                           unsigned short* __restrict__ csr16) {
    const int bid = blockIdx.x;
    const int t = bid & 15;
    const int i = bid >> 4;
    const int e = i * 256 + threadIdx.x;
    const int* ep = ei + (size_t)t * 2 * N_EDGES;
    int s = ep[e], d = ep[N_EDGES + e];
    int b = e / CSR_EPB;
    unsigned int pos = partial[((size_t)t * CSR_NB + b) * N_NODES + d]
                     + lrank16[(size_t)t * N_EDGES + e];
    csr16[(size_t)t * EPN + pos] = (unsigned short)s;
}

// ---------------- MFMA GEMM (+fused attention-dot epilogue) ----------------
// BM=128, BN templated; AF32: A rows fp32 split hi/lo in-register.
// DT: 0 = bf16 MFMA, 1 = fp16 MFMA (A/B are raw 16-bit lanes either way).

template <bool XMAP, bool ATTN, bool CHALF, int BN, bool AF32, int DT>
__global__ __launch_bounds__(256) void k_gemm_mfma(const unsigned short* __restrict__ A, int lda,
                                                   const unsigned short* __restrict__ Bt,
                                                   float* __restrict__ C, int ldc,
                                                   int K2, int tbase,
                                                   const float* __restrict__ a_src,
                                                   const float* __restrict__ a_dst,
                                                   float* __restrict__ asb,
                                                   float* __restrict__ adb) {
    __shared__ unsigned short sA[128][40];
    __shared__ unsigned short sB[BN][40];
    const int NJ = BN / 16;
    const int tid = threadIdx.x;
    const int wid = tid >> 6, lane = tid & 63;
    const int row0 = blockIdx.y * 128;
    const int col0 = blockIdx.x * BN;

    const int ar = tid >> 1, aq = (tid & 1) * 8;
    const int bc = tid >> 2, bq = (tid & 3) * 8;

    int l = row0 + ar;
    int rg;
    if (XMAP) { int tl = l / N_NODES; int s = l - tl * N_NODES; rg = s * T_STEPS + tbase + tl; }
    else rg = l;
    const unsigned short* Arow = A + (size_t)rg * lda;
    const float* Arowf = (const float*)A + (size_t)rg * lda;
    const unsigned short* Brow = Bt + (size_t)(col0 + bc) * K2;
    const unsigned short* Brow2 = (BN == 128) ? (Bt + (size_t)(col0 + bc + 64) * K2) : Brow;

    const int fr = lane & 15;
    const int kg = lane >> 4;

    f32x4 acc[2][NJ] = {};

    for (int kk = 0; kk < K2; kk += 32) {
        ushort8 a0, a1;
        if (AF32) {
            float4 fa0 = *(const float4*)(Arowf + ((kk + aq) >> 1));
            float4 fa1 = *(const float4*)(Arowf + ((kk + aq) >> 1) + 8);
            a0 = f4_to_hilo(fa0);
            a1 = f4_to_hilo(fa1);
        } else {
            a0 = *(const ushort8*)(Arow + kk + aq);
            a1 = *(const ushort8*)(Arow + kk + aq + 16);
        }
        ushort8 b0 = *(const ushort8*)(Brow + kk + bq);
        ushort8 b1;
        if (BN == 128) b1 = *(const ushort8*)(Brow2 + kk + bq);
        *(ushort8*)&sA[ar][aq] = a0;
        *(ushort8*)&sA[ar][aq + 16] = a1;
        *(ushort8*)&sB[bc][bq] = b0;
        if (BN == 128) *(ushort8*)&sB[bc + 64][bq] = b1;
        __syncthreads();
        bf16x8 af[2], bfv[NJ];
#pragma unroll
        for (int i = 0; i < 2; ++i)
            af[i] = *(const bf16x8*)&sA[wid * 32 + i * 16 + fr][kg * 8];
#pragma unroll
        for (int j = 0; j < NJ; ++j)
            bfv[j] = *(const bf16x8*)&sB[j * 16 + fr][kg * 8];
#pragma unroll
        for (int i = 0; i < 2; ++i)
#pragma unroll
            for (int j = 0; j < NJ; ++j) {
                if (DT == 0)
                    acc[i][j] = __builtin_amdgcn_mfma_f32_16x16x32_bf16(af[i], bfv[j],
                                                                        acc[i][j], 0, 0, 0);
                else
                    acc[i][j] = __builtin_amdgcn_mfma_f32_16x16x32_f16(
                        __builtin_bit_cast(half8, af[i]), __builtin_bit_cast(half8, bfv[j]),
                        acc[i][j], 0, 0, 0);
            }
        __syncthreads();
    }
#pragma unroll
    for (int i = 0; i < 2; ++i)
#pragma unroll
        for (int j = 0; j < NJ; ++j) {
            int col = col0 + j * 16 + fr;
#pragma unroll
            for (int r = 0; r < 4; ++r) {
                int row = row0 + wid * 32 + i * 16 + kg * 4 + r;
                if (CHALF) {
                    _Float16* Ch = (_Float16*)C;
                    Ch[(size_t)row * ldc + col] = (_Float16)acc[i][j][r];
                } else {
                    C[(size_t)row * ldc + col] = acc[i][j][r];
                }
            }
        }

    if (ATTN) {
#pragma unroll
        for (int half = 0; half < BN / 64; ++half) {
            const int h_idx = (col0 >> 6) + half;
            float wa[4], wb[4];
#pragma unroll
            for (int j = 0; j < 4; ++j) {
                wa[j] = a_src[h_idx * 64 + j * 16 + fr];
                wb[j] = a_dst[h_idx * 64 + j * 16 + fr];
            }
#pragma unroll
            for (int i = 0; i < 2; ++i)
#pragma unroll
                for (int r = 0; r < 4; ++r) {
                    float sa = 0.f, sd = 0.f;
#pragma unroll
                    for (int j = 0; j < 4; ++j) {
                        sa = fmaf(acc[i][half * 4 + j][r], wa[j], sa);
                        sd = fmaf(acc[i][half * 4 + j][r], wb[j], sd);
                    }
#pragma unroll
                    for (int s = 1; s <= 8; s <<= 1) {
                        sa += __shfl_xor(sa, s, 64);
                        sd += __shfl_xor(sd, s, 64);
                    }
                    if (fr == 0) {
                        int row = row0 + wid * 32 + i * 16 + kg * 4 + r;
                        asb[(size_t)row * 4 + h_idx] = sa;
                        adb[(size_t)row * 4 + h_idx] = sd;
                    }
                }
        }
    }
}

// ---------------- GAT aggregation: chunk-level software pipeline; fp16 outputs ----------------

template <bool CONCAT>
__global__ __launch_bounds__(256) void k_agg(const _Float16* __restrict__ hfeat,
                                             const float* __restrict__ asb,
                                             const float* __restrict__ adb,
                                             const int* __restrict__ off_all,
                                             const unsigned short* __restrict__ csr16,
                                             const float* __restrict__ bias,
                                             _Float16* __restrict__ out, int tbase) {
    const int bid = blockIdx.x;
    const int tl = bid & 7;
    const int nb = bid >> 3;
    const int t = tbase + tl;
    const int wid = threadIdx.x >> 6;
    const int d = nb * 4 + wid;
    const int lane = threadIdx.x & 63;
    const int h = lane >> 4;
    const int e16 = lane & 15;
    const int* off = off_all + (size_t)t * (N_NODES + 1);
    const int beg = off[d];
    const int deg = off[d + 1] - beg;
    const unsigned short* cs = csr16 + (size_t)t * EPN + beg;
    const float* asl = asb + (size_t)tl * N_NODES * HEADS;
    const half4* feat = (const half4*)(hfeat + (size_t)tl * N_NODES * HC) + lane;
    const float adh = adb[((size_t)tl * N_NODES + d) * HEADS + h];

    float ax = 0.f, ay = 0.f, az = 0.f, aw = 0.f, dlane = 0.f;
    const int widx = (lane & 48);

    // prologue: chunk 0 score loads
    int sreg = 0;
    float araw = 0.f;
    if (e16 < deg) {
        sreg = cs[e16];
        araw = asl[sreg * 4 + h];
    }

    for (int base = 0; base < deg; base += 16) {
        float wme = 0.f;
        if (base + e16 < deg) {
            float sc = araw + adh;
            sc = sc > 0.f ? sc : 0.2f * sc;
            wme = __expf(sc);
        }
        dlane += wme;

        int nxt = base + 16;
        int sregN = 0;
        float arawN = 0.f;
        if (nxt + e16 < deg) {
            sregN = cs[nxt + e16];
            arawN = asl[sregN * 4 + h];
        }

        const int len = min(16, deg - base);
        int q = 0;
        for (; q + 4 <= len; q += 4) {
#pragma unroll
            for (int u = 0; u < 4; ++u) {
                int qq = q + u;
                float wq = __shfl(wme, widx | qq, 64);
                int sq = __builtin_amdgcn_readlane(sreg, qq);
                half4 v = feat[(size_t)sq * 64];
                ax = fmaf(wq, (float)v[0], ax);
                ay = fmaf(wq, (float)v[1], ay);
                az = fmaf(wq, (float)v[2], az);
                aw = fmaf(wq, (float)v[3], aw);
            }
        }
        for (; q < len; ++q) {
            float wq = __shfl(wme, widx | q, 64);
            int sq = __builtin_amdgcn_readlane(sreg, q);
            half4 v = feat[(size_t)sq * 64];
            ax = fmaf(wq, (float)v[0], ax);
            ay = fmaf(wq, (float)v[1], ay);
            az = fmaf(wq, (float)v[2], az);
            aw = fmaf(wq, (float)v[3], aw);
        }
        sreg = sregN;
        araw = arawN;
    }
    float denom = dlane;
#pragma unroll
    for (int s = 1; s <= 8; s <<= 1) denom += __shfl_xor(denom, s, 64);
    float inv = 1.f / (denom + 1e-16f);
    ax *= inv; ay *= inv; az *= inv; aw *= inv;

    if (CONCAT) {
        float4 b = ((const float4*)bias)[lane];
        half4 o;
        o[0] = (_Float16)fmaxf(ax + b.x, 0.f);
        o[1] = (_Float16)fmaxf(ay + b.y, 0.f);
        o[2] = (_Float16)fmaxf(az + b.z, 0.f);
        o[3] = (_Float16)fmaxf(aw + b.w, 0.f);
        *(half4*)(out + ((size_t)tl * N_NODES + d) * HC + lane * 4) = o;
    } else {
        ax += __shfl_xor(ax, 16, 64); ax += __shfl_xor(ax, 32, 64);
        ay += __shfl_xor(ay, 16, 64); ay += __shfl_xor(ay, 32, 64);
        az += __shfl_xor(az, 16, 64); az += __shfl_xor(az, 32, 64);
        aw += __shfl_xor(aw, 16, 64); aw += __shfl_xor(aw, 32, 64);
        if (h == 0) {
            float4 b = ((const float4*)bias)[e16];
            half4 o;
            o[0] = (_Float16)fmaxf(ax * 0.25f + b.x, 0.f);
            o[1] = (_Float16)fmaxf(ay * 0.25f + b.y, 0.f);
            o[2] = (_Float16)fmaxf(az * 0.25f + b.z, 0.f);
            o[3] = (_Float16)fmaxf(aw * 0.25f + b.w, 0.f);
            *(half4*)(out + ((size_t)d * T_STEPS + t) * CDIM + e16 * 4) = o;
        }
    }
}

// ---------------- persistent GRU (h-side GEMV only) + final linear ----------------
// GI stored fp16 (pre-activation gate values, |gi| small); upconvert on load.

#define GRU_NPB 40
#define GRU_THREADS 512

__global__ __launch_bounds__(GRU_THREADS, 4) void k_gru_all(const _Float16* __restrict__ GI,
                                                            const float* __restrict__ Whh,
                                                            const float* __restrict__ bih,
                                                            const float* __restrict__ bhh,
                                                            const float* __restrict__ Wout,
                                                            const float* __restrict__ bout,
                                                            float* __restrict__ out) {
    __shared__ f32x4 sWp[16 * 3 * 64];   // 48 KB: [k4][p][c]
    __shared__ float sH[GRU_NPB][68];
    const int tid = threadIdx.x;
    const int c = tid & 63;
    const int ng = tid >> 6;
    const int n0 = ng * 5;
    const int nid0 = blockIdx.x * GRU_NPB + n0;

    for (int i = tid; i < 16 * 3 * 64; i += GRU_THREADS) {
        int k4 = i / 192, rem = i - k4 * 192;
        int pp = rem >> 6, cc = rem & 63;
        f32x4 w;
#pragma unroll
        for (int q = 0; q < 4; ++q) w[q] = Whh[(k4 * 4 + q) * G3 + pp * 64 + cc];
        sWp[i] = w;
    }
    for (int i = tid; i < GRU_NPB * 68; i += GRU_THREADS) ((float*)sH)[i] = 0.f;
    __syncthreads();

    const float bi0 = bih[c], bi1 = bih[64 + c], bi2 = bih[128 + c];
    const float bh0 = bhh[c], bh1 = bhh[64 + c], bh2 = bhh[128 + c];

    for (int t = 0; t < T_STEPS; ++t) {
        float gi0[5], gi1[5], gi2[5];
#pragma unroll
        for (int n = 0; n < 5; ++n) {
            const _Float16* gp = GI + ((size_t)(nid0 + n) * T_STEPS + t) * G3;
            gi0[n] = (float)gp[c]; gi1[n] = (float)gp[64 + c]; gi2[n] = (float)gp[128 + c];
        }
        float a0[5] = {}, a1[5] = {}, a2[5] = {};
#pragma unroll 4
        for (int k4 = 0; k4 < 16; ++k4) {
            f32x4 h4[5];
#pragma unroll
            for (int n = 0; n < 5; ++n) h4[n] = *(const f32x4*)&sH[n0 + n][k4 * 4];
            f32x4 w0 = sWp[(k4 * 3 + 0) * 64 + c];
            f32x4 w1 = sWp[(k4 * 3 + 1) * 64 + c];
            f32x4 w2 = sWp[(k4 * 3 + 2) * 64 + c];
#pragma unroll
            for (int q = 0; q < 4; ++q)
#pragma unroll
                for (int n = 0; n < 5; ++n) {
                    float hv = h4[n][q];
                    a0[n] = fmaf(hv, w0[q], a0[n]);
                    a1[n] = fmaf(hv, w1[q], a1[n]);
                    a2[n] = fmaf(hv, w2[q], a2[n]);
                }
        }
#pragma unroll
        for (int n = 0; n < 5; ++n) {
            float r = fsig(gi0[n] + bi0 + a0[n] + bh0);
            float z = fsig(gi1[n] + bi1 + a1[n] + bh1);
            float g = ftanh(gi2[n] + bi2 + r * (a2[n] + bh2));
            sH[n0 + n][c] = (1.f - z) * g + z * sH[n0 + n][c];
        }
    }

    float wc = Wout[c];
    float b0 = bout[0];
#pragma unroll
    for (int n = 0; n < 5; ++n) {
        float v = sH[n0 + n][c] * wc;
#pragma unroll
        for (int s = 32; s >= 1; s >>= 1) v += __shfl_xor(v, s, 64);
        if (c == 0) out[nid0 + n] = v + b0;
    }
}

// ---------------- launch ----------------

extern "C" void kernel_launch(void* const* d_in, const int* in_sizes, int n_in,
                              void* d_out, int out_size, void* d_ws, size_t ws_size,
                              hipStream_t stream) {
    const float* x   = (const float*)d_in[0];
    const int*   ei  = (const int*)d_in[1];
    const float* W1  = (const float*)d_in[2];
    const float* as1 = (const float*)d_in[3];
    const float* ad1 = (const float*)d_in[4];
    const float* b1  = (const float*)d_in[5];
    const float* W2  = (const float*)d_in[6];
    const float* as2 = (const float*)d_in[7];
    const float* ad2 = (const float*)d_in[8];
    const float* b2  = (const float*)d_in[9];
    const float* Wih = (const float*)d_in[10];
    const float* Whh = (const float*)d_in[11];
    const float* bih = (const float*)d_in[12];
    const float* bhh = (const float*)d_in[13];
    const float* Wout = (const float*)d_in[14];
    const float* bout = (const float*)d_in[15];

    char* p = (char*)d_ws;
    _Float16* h_half = (_Float16*)p;  p += 81920000;   // [8][20000][256] fp16
    _Float16* g1_f16 = (_Float16*)p;  p += 81920000;   // [8][20000][256] fp16
    _Float16* g2_f16 = (_Float16*)p;  p += 40960000;   // [20000][16][64] fp16
    _Float16* GI_all = (_Float16*)p;  p += 122880000;  // [320000][192] fp16
    float* asb = (float*)p;  p += 2560000;
    float* adb = (float*)p;  p += 2560000;
    unsigned short* w1t = (unsigned short*)p;  p += 131072;   // 256 x 256 bf16 hilo
    _Float16* w2h = (_Float16*)p;  p += 131072;               // 256 x 256 fp16
    _Float16* wihh = (_Float16*)p;  p += 24576;               // 192 x 64 fp16
    int* off_all = (int*)p;  p += 1280064;
    unsigned short* csr16 = (unsigned short*)p;  p += 10880000;
    unsigned int* partial = (unsigned int*)p;  p += (size_t)T_STEPS * CSR_NB * N_NODES * 4;
    unsigned int* total = (unsigned int*)p;  p += (size_t)T_STEPS * N_NODES * 4;
    unsigned short* lrank16 = (unsigned short*)p;  p += (size_t)T_STEPS * N_EDGES * 2;

    dim3 thr(256);

    // weight conversions
    k_wsplit<<<(F_INDIM * HC + 255) / 256, thr, 0, stream>>>(W1, w1t, F_INDIM, HC);
    k_whalf<<<(HC * HC + 255) / 256, thr, 0, stream>>>(W2, w2h, HC, HC);
    k_whalf<<<(CDIM * G3 + 255) / 256, thr, 0, stream>>>(Wih, wihh, CDIM, G3);

    // CSR: hist(+lrank) -> colscan -> scan -> fold -> parallel scatter fill
    k_csr_hist<<<dim3(CSR_NB, T_STEPS), 1024, 0, stream>>>(ei, partial, lrank16);
    k_csr_colscan<<<(T_STEPS * N_NODES + 255) / 256, thr, 0, stream>>>(partial, total);
    k_csr_scan<<<T_STEPS, 1024, 0, stream>>>(total, off_all, csr16);
    k_csr_fold<<<(T_STEPS * CSR_NB * N_NODES + 255) / 256, thr, 0, stream>>>(partial, off_all);
    k_csr_fill<<<(N_EDGES / 256) * T_STEPS, thr, 0, stream>>>(ei, partial, lrank16, csr16);

    for (int hb = 0; hb < 2; ++hb) {
        const int tbase = hb * TB;
        // GAT layer 1: fp32 x staged+split in-kernel (bf16 hilo MFMA); fp16 feature out
        k_gemm_mfma<true, true, true, 128, true, 0><<<dim3(2, RB_ROWS / 128), thr, 0, stream>>>(
            (const unsigned short*)x, F_INDIM, w1t, (float*)h_half, HC, 2 * F_INDIM, tbase,
            as1, ad1, asb, adb);
        k_agg<true><<<N_NODES / 4 * TB, thr, 0, stream>>>(
            h_half, asb, adb, off_all, csr16, b1, g1_f16, tbase);
        // GAT layer 2: fp16 x fp16 MFMA, K=256
        k_gemm_mfma<false, true, true, 128, false, 1><<<dim3(2, RB_ROWS / 128), thr, 0, stream>>>(
            (const unsigned short*)g1_f16, HC, (const unsigned short*)w2h, (float*)h_half, HC,
            HC, tbase, as2, ad2, asb, adb);
        k_agg<false><<<N_NODES / 4 * TB, thr, 0, stream>>>(
            h_half, asb, adb, off_all, csr16, b2, g2_f16, tbase);
    }

    // GI = g2 @ Wih for all (node, t) rows: fp16 MFMA, K=64, fp16 output
    k_gemm_mfma<false, false, true, 64, false, 1><<<dim3(3, N_NODES * T_STEPS / 128), thr, 0,
                                                    stream>>>(
        (const unsigned short*)g2_f16, CDIM, (const unsigned short*)wihh, (float*)GI_all, G3,
        CDIM, 0, nullptr, nullptr, nullptr, nullptr);

    k_gru_all<<<N_NODES / GRU_NPB, GRU_THREADS, 0, stream>>>(GI_all, Whh, bih, bhh, Wout, bout,
                                                            (float*)d_out);
}